// Round 7
// baseline (1972.537 us; speedup 1.0000x reference)
//
#include <hip/hip_runtime.h>

// Round 7: (a) revert R6's K-from-global regression (uncoalesced 6KB-stride
// per-lane K reads -> VMEM-bound, 386us); attn back to R5 structure (239us)
// with ONE fix: V tiles swizzle with H(r)=(r^(r>>2))&7 instead of r&7. R6
// proved conflicts (3.36e7, unchanged when K-LDS was deleted) live in the
// V-transpose writes, whose rows stride 4 -> (r&7) spans only 2 values.
// New hash spans 8 on both the write rows (4ml+dd) and read rows (16j+ml).
// (b) bgemm_bt BK 32->64 (pitch-72 LDS, 36KB): halves barrier count, 32
// MFMA per barrier-pair. Accumulation order identical -> bitwise same C.

typedef unsigned short u16;
typedef short bf16x8 __attribute__((ext_vector_type(8)));
typedef float f32x4 __attribute__((ext_vector_type(4)));
typedef _Float16 f16;
typedef f16 f16x8 __attribute__((ext_vector_type(8)));
typedef f16 f16x4 __attribute__((ext_vector_type(4)));
typedef f16 f16x2 __attribute__((ext_vector_type(2)));

#define T_TOKENS 4096
#define SEQ      2048
#define CAPACITY 1280

__device__ __forceinline__ u16 f2bf(float f) {
  unsigned int u = __float_as_uint(f);
  return (u16)((u + 0x7FFFu + ((u >> 16) & 1u)) >> 16);
}
__device__ __forceinline__ float bf2f(u16 h) {
  return __uint_as_float(((unsigned int)h) << 16);
}
__device__ __forceinline__ float gelu_f(float x) {
  float x3 = x * x * x;
  float t = tanhf(0.7978845608028654f * (x + 0.044715f * x3));
  return 0.5f * x * (1.0f + t);
}

// ---------------- LayerNorm (fp32 in; f32 / bf16 / split-f16 out) ----------
__global__ __launch_bounds__(256) void ln_kernel(
    const float* __restrict__ x, const float* __restrict__ g,
    const float* __restrict__ bt, float* __restrict__ of32,
    u16* __restrict__ obf, f16* __restrict__ oh, f16* __restrict__ ol) {
  const int t = blockIdx.x, tid = threadIdx.x;
  float4 v = ((const float4*)(x + (size_t)t * 1024))[tid];
  float s = v.x + v.y + v.z + v.w;
  float sq = v.x * v.x + v.y * v.y + v.z * v.z + v.w * v.w;
#pragma unroll
  for (int d = 1; d < 64; d <<= 1) {
    s += __shfl_xor(s, d);
    sq += __shfl_xor(sq, d);
  }
  __shared__ float red[8];
  if ((tid & 63) == 0) { red[tid >> 6] = s; red[4 + (tid >> 6)] = sq; }
  __syncthreads();
  s = red[0] + red[1] + red[2] + red[3];
  sq = red[4] + red[5] + red[6] + red[7];
  const float mu = s * (1.0f / 1024.0f);
  const float var = sq * (1.0f / 1024.0f) - mu * mu;
  const float rs = rsqrtf(var + 1e-6f);
  float4 gv = ((const float4*)g)[tid];
  float4 bv = ((const float4*)bt)[tid];
  float4 o;
  o.x = (v.x - mu) * rs * gv.x + bv.x;
  o.y = (v.y - mu) * rs * gv.y + bv.y;
  o.z = (v.z - mu) * rs * gv.z + bv.z;
  o.w = (v.w - mu) * rs * gv.w + bv.w;
  if (of32) ((float4*)(of32 + (size_t)t * 1024))[tid] = o;
  if (obf) {
    ushort4 ob;
    ob.x = f2bf(o.x); ob.y = f2bf(o.y); ob.z = f2bf(o.z); ob.w = f2bf(o.w);
    ((ushort4*)(obf + (size_t)t * 1024))[tid] = ob;
  }
  if (oh) {
    const float f[4] = {o.x, o.y, o.z, o.w};
    f16x4 hv, lv;
#pragma unroll
    for (int i = 0; i < 4; ++i) {
      f16 hi = (f16)f[i];
      hv[i] = hi;
      lv[i] = (f16)(f[i] - (float)hi);
    }
    ((f16x4*)(oh + (size_t)t * 1024))[tid] = hv;
    ((f16x4*)(ol + (size_t)t * 1024))[tid] = lv;
  }
}

// ------- transpose fp32 [R][C] -> f16 hi/lo [C][R] (weight prep) ----------
__global__ __launch_bounds__(256) void transpose_f32_f16hl(
    const float* __restrict__ in, f16* __restrict__ outh, f16* __restrict__ outl,
    int R, int C) {
  __shared__ float tile[32][33];
  const int c0 = blockIdx.x * 32, r0 = blockIdx.y * 32;
  const int tx = threadIdx.x & 31, ty = threadIdx.x >> 5;
#pragma unroll
  for (int i = 0; i < 32; i += 8)
    tile[ty + i][tx] = in[(size_t)(r0 + ty + i) * C + c0 + tx];
  __syncthreads();
#pragma unroll
  for (int i = 0; i < 32; i += 8) {
    const float v = tile[tx][ty + i];
    const f16 hi = (f16)v;
    const size_t idx = (size_t)(c0 + ty + i) * R + r0 + tx;
    outh[idx] = hi;
    outl[idx] = (f16)(v - (float)hi);
  }
}

// ------- split-fp16 3-pass MFMA GEMM, pre-split A planes -------------------
// EPI=0: write split-f16 C planes (Ch/Cl). EPI=1: write f32 C (+res).
template <int EPI>
__global__ __launch_bounds__(256, 2) void gemm_f16x3_bt(
    const f16* __restrict__ Agh, const f16* __restrict__ Agl,
    const f16* __restrict__ Bth, const f16* __restrict__ Btl,
    const float* __restrict__ bias, const float* __restrict__ res,
    float* __restrict__ C, f16* __restrict__ Ch, f16* __restrict__ Cl,
    int M, int N, int K) {
  __shared__ f16 Ah[128 * 40], Al[128 * 40], Bh[128 * 40], Bl[128 * 40];
  const int tid = threadIdx.x, lane = tid & 63, w = tid >> 6;
  const int qd = lane >> 4, ml = lane & 15;
  const int m0 = blockIdx.y * 128, n0 = blockIdx.x * 128;
  const int wm = (w & 1) * 64, wn = (w >> 1) * 64;
  f32x4 acc[4][4] = {};

  const int sr = tid >> 1, sc = (tid & 1) * 16;
  const f16* gAh = Agh + (size_t)(m0 + sr) * K + sc;
  const f16* gAl = Agl + (size_t)(m0 + sr) * K + sc;
  const f16* gBh = Bth + (size_t)(n0 + sr) * K + sc;
  const f16* gBl = Btl + (size_t)(n0 + sr) * K + sc;
  f16* lAh = &Ah[sr * 40 + sc];
  f16* lAl = &Al[sr * 40 + sc];
  f16* lBh = &Bh[sr * 40 + sc];
  f16* lBl = &Bl[sr * 40 + sc];

  for (int k0 = 0; k0 < K; k0 += 32) {
    const uint4 ah0 = *(const uint4*)(gAh + k0);
    const uint4 ah1 = *(const uint4*)(gAh + k0 + 8);
    const uint4 al0 = *(const uint4*)(gAl + k0);
    const uint4 al1 = *(const uint4*)(gAl + k0 + 8);
    const uint4 bh0 = *(const uint4*)(gBh + k0);
    const uint4 bh1 = *(const uint4*)(gBh + k0 + 8);
    const uint4 bl0 = *(const uint4*)(gBl + k0);
    const uint4 bl1 = *(const uint4*)(gBl + k0 + 8);
    __syncthreads();
    *(uint4*)lAh = ah0; *(uint4*)(lAh + 8) = ah1;
    *(uint4*)lAl = al0; *(uint4*)(lAl + 8) = al1;
    *(uint4*)lBh = bh0; *(uint4*)(lBh + 8) = bh1;
    *(uint4*)lBl = bl0; *(uint4*)(lBl + 8) = bl1;
    __syncthreads();
    f16x8 fah[4], fal[4], fbh[4], fbl[4];
#pragma unroll
    for (int i = 0; i < 4; ++i) {
      fah[i] = *(const f16x8*)&Ah[(wm + i * 16 + ml) * 40 + qd * 8];
      fal[i] = *(const f16x8*)&Al[(wm + i * 16 + ml) * 40 + qd * 8];
    }
#pragma unroll
    for (int j = 0; j < 4; ++j) {
      fbh[j] = *(const f16x8*)&Bh[(wn + j * 16 + ml) * 40 + qd * 8];
      fbl[j] = *(const f16x8*)&Bl[(wn + j * 16 + ml) * 40 + qd * 8];
    }
#pragma unroll
    for (int i = 0; i < 4; ++i)
#pragma unroll
      for (int j = 0; j < 4; ++j) {
        acc[i][j] = __builtin_amdgcn_mfma_f32_16x16x32_f16(fah[i], fbh[j], acc[i][j], 0, 0, 0);
        acc[i][j] = __builtin_amdgcn_mfma_f32_16x16x32_f16(fah[i], fbl[j], acc[i][j], 0, 0, 0);
        acc[i][j] = __builtin_amdgcn_mfma_f32_16x16x32_f16(fal[i], fbh[j], acc[i][j], 0, 0, 0);
      }
  }
#pragma unroll
  for (int i = 0; i < 4; ++i) {
    const int rr = m0 + wm + i * 16 + qd * 4;
#pragma unroll
    for (int j = 0; j < 4; ++j) {
      const int cc = n0 + wn + j * 16 + ml;
      const float bb = bias[cc];
#pragma unroll
      for (int p = 0; p < 4; ++p) {
        float v = acc[i][j][p] + bb;
        const size_t idx = (size_t)(rr + p) * N + cc;
        if (EPI == 1) {
          C[idx] = v + res[idx];
        } else {
          const f16 hi = (f16)v;
          Ch[idx] = hi;
          Cl[idx] = (f16)(v - (float)hi);
        }
      }
    }
  }
}

// ---------------- RoPE (in-place on split-f16 qkv planes, q scaled 1/8) ----
__global__ __launch_bounds__(256) void rope_kernel(
    f16* __restrict__ qh, f16* __restrict__ ql, const float* __restrict__ cosb,
    const float* __restrict__ sinb) {
  const int t = blockIdx.x;
  const int s = t & (SEQ - 1);
  f16* rh = qh + (size_t)t * 3072;
  f16* rl = ql + (size_t)t * 3072;
  const int tid = threadIdx.x;
#pragma unroll
  for (int it = 0; it < 2; ++it) {
    const int p = tid + it * 256;            // 512 pair-pairs (q,k sections)
    const int sec = p >> 8;                  // 0=q, 1=k
    const int rem = p & 255;
    const int hd = rem >> 4, d = (rem & 15) * 2;
    const int col = sec * 1024 + hd * 64 + d;
    const float c1a = cosb[s * 64 + d], s1a = sinb[s * 64 + d];
    const float c1b = cosb[s * 64 + d + 1], s1b = sinb[s * 64 + d + 1];
    const float c2a = cosb[s * 64 + d + 32], s2a = sinb[s * 64 + d + 32];
    const float c2b = cosb[s * 64 + d + 33], s2b = sinb[s * 64 + d + 33];
    const f16x2 ah = *(const f16x2*)(rh + col);
    const f16x2 al = *(const f16x2*)(rl + col);
    const f16x2 bh = *(const f16x2*)(rh + col + 32);
    const f16x2 bl = *(const f16x2*)(rl + col + 32);
    const float a0 = (float)ah[0] + (float)al[0];
    const float a1 = (float)ah[1] + (float)al[1];
    const float b0 = (float)bh[0] + (float)bl[0];
    const float b1 = (float)bh[1] + (float)bl[1];
    float na0 = a0 * c1a - b0 * s1a;
    float na1 = a1 * c1b - b1 * s1b;
    float nb0 = b0 * c2a + a0 * s2a;
    float nb1 = b1 * c2b + a1 * s2b;
    if (sec == 0) { na0 *= 0.125f; na1 *= 0.125f; nb0 *= 0.125f; nb1 *= 0.125f; }
    f16x2 nah, nal, nbh, nbl;
    nah[0] = (f16)na0; nal[0] = (f16)(na0 - (float)nah[0]);
    nah[1] = (f16)na1; nal[1] = (f16)(na1 - (float)nah[1]);
    nbh[0] = (f16)nb0; nbl[0] = (f16)(nb0 - (float)nbh[0]);
    nbh[1] = (f16)nb1; nbl[1] = (f16)(nb1 - (float)nbh[1]);
    *(f16x2*)(rh + col) = nah;
    *(f16x2*)(rl + col) = nal;
    *(f16x2*)(rh + col + 32) = nbh;
    *(f16x2*)(rl + col + 32) = nbl;
  }
}

// ---------------- split-fp16 MFMA flash attention (swapped QK^T) -----------
__global__ __launch_bounds__(256) void attn_mfma(
    const f16* __restrict__ qkvh, const f16* __restrict__ qkvl,
    f16* __restrict__ ogh, f16* __restrict__ ogl) {
  const int bh_ = blockIdx.y, b = bh_ >> 4, h = bh_ & 15;
  const int tid = threadIdx.x, w = tid >> 6, lane = tid & 63;
  const int quad = lane >> 4, ml = lane & 15;
  const int q0 = blockIdx.x * 64;
  const f16* baseh = qkvh + (size_t)b * SEQ * 3072 + h * 64;
  const f16* basel = qkvl + (size_t)b * SEQ * 3072 + h * 64;

  // Unpadded [64][64] tiles, 16B-granular XOR swizzles. K/P rows are lane-
  // stride-1 -> (r&7) hash spreads fine. V rows are lane-stride-4 (vr=4ml+dd)
  // -> (r&7) spans only 2 values (R6 counter evidence: conflicts unchanged
  // when K-LDS removed); (r^(r>>2))&7 spans 8 on both vr=4ml+dd and 16j+ml.
  __shared__ f16 Kh[64 * 64], Kl[64 * 64];     // [key][d]
  __shared__ f16 Vh[64 * 64], Vl[64 * 64];     // [d][key]
  __shared__ f16 Ph[4][16 * 64], Pl[4][16 * 64];  // per-warp [q][key]

#define SWZ(r, c) ((c) ^ (((r) & 7) << 3))
#define SWZV(r, c) ((c) ^ ((((r) ^ ((r) >> 2)) & 7) << 3))

  f16x8 qh[2], ql[2];
  {
    const f16* qrh = baseh + (size_t)(q0 + w * 16 + ml) * 3072;
    const f16* qrl = basel + (size_t)(q0 + w * 16 + ml) * 3072;
#pragma unroll
    for (int ks = 0; ks < 2; ++ks) {
      qh[ks] = *(const f16x8*)(qrh + ks * 32 + quad * 8);
      ql[ks] = *(const f16x8*)(qrl + ks * 32 + quad * 8);
    }
  }

  float m_i = -1e30f, l_i = 0.f;   // online stats for q-row = q0+w*16+ml
  f32x4 accO[4] = {};

  const int skey = tid >> 2, scg = (tid & 3) * 16;
  const int sd0 = (tid & 15) * 4, sk0 = (tid >> 4) * 4;

  for (int c0 = 0; c0 < SEQ; c0 += 64) {
    __syncthreads();
    {
      const f16* krh = baseh + 1024 + (size_t)(c0 + skey) * 3072 + scg;
      const f16* krl = basel + 1024 + (size_t)(c0 + skey) * 3072 + scg;
      *(f16x8*)&Kh[skey * 64 + SWZ(skey, scg)] = *(const f16x8*)krh;
      *(f16x8*)&Kh[skey * 64 + SWZ(skey, scg + 8)] = *(const f16x8*)(krh + 8);
      *(f16x8*)&Kl[skey * 64 + SWZ(skey, scg)] = *(const f16x8*)krl;
      *(f16x8*)&Kl[skey * 64 + SWZ(skey, scg + 8)] = *(const f16x8*)(krl + 8);

      f16x4 rvh[4], rvl[4];
#pragma unroll
      for (int i = 0; i < 4; ++i) {
        rvh[i] = *(const f16x4*)(baseh + 2048 + (size_t)(c0 + sk0 + i) * 3072 + sd0);
        rvl[i] = *(const f16x4*)(basel + 2048 + (size_t)(c0 + sk0 + i) * 3072 + sd0);
      }
#pragma unroll
      for (int dd = 0; dd < 4; ++dd) {
        f16x4 vh4, vl4;
#pragma unroll
        for (int i = 0; i < 4; ++i) { vh4[i] = rvh[i][dd]; vl4[i] = rvl[i][dd]; }
        const int vr = sd0 + dd;
        *(f16x4*)&Vh[vr * 64 + SWZV(vr, sk0)] = vh4;
        *(f16x4*)&Vl[vr * 64 + SWZV(vr, sk0)] = vl4;
      }
    }
    __syncthreads();

    // Swapped QK^T: s[j][p] = S^T[k = 16j+4*quad+p][q = ml].
    f32x4 s[4] = {};
#pragma unroll
    for (int ks = 0; ks < 2; ++ks)
#pragma unroll
      for (int j = 0; j < 4; ++j) {
        const int kr = j * 16 + ml;
        const f16x8 kh = *(const f16x8*)&Kh[kr * 64 + SWZ(kr, ks * 32 + quad * 8)];
        const f16x8 kl = *(const f16x8*)&Kl[kr * 64 + SWZ(kr, ks * 32 + quad * 8)];
        s[j] = __builtin_amdgcn_mfma_f32_16x16x32_f16(kh, qh[ks], s[j], 0, 0, 0);
        s[j] = __builtin_amdgcn_mfma_f32_16x16x32_f16(kl, qh[ks], s[j], 0, 0, 0);
        s[j] = __builtin_amdgcn_mfma_f32_16x16x32_f16(kh, ql[ks], s[j], 0, 0, 0);
      }

    // Online softmax: one q per lane -> scalar stats, 2 shfl per reduce.
    float pmax = s[0][0];
#pragma unroll
    for (int j = 0; j < 4; ++j)
#pragma unroll
      for (int p = 0; p < 4; ++p) pmax = fmaxf(pmax, s[j][p]);
    pmax = fmaxf(pmax, __shfl_xor(pmax, 16));
    pmax = fmaxf(pmax, __shfl_xor(pmax, 32));
    const float mn = fmaxf(m_i, pmax);
    const float al = __expf(m_i - mn);
    float rs = 0.f;
#pragma unroll
    for (int j = 0; j < 4; ++j)
#pragma unroll
      for (int p = 0; p < 4; ++p) {
        const float e = __expf(s[j][p] - mn);
        s[j][p] = e;
        rs += e;
      }
    rs += __shfl_xor(rs, 16);
    rs += __shfl_xor(rs, 32);
    m_i = mn;
    l_i = l_i * al + rs;

    // alpha lives at lane(q=ml); accO needs it at q=4*quad+p.
    float alpha_p[4];
#pragma unroll
    for (int p = 0; p < 4; ++p) alpha_p[p] = __shfl(al, 20 * quad + p);
#pragma unroll
    for (int j = 0; j < 4; ++j)
#pragma unroll
      for (int p = 0; p < 4; ++p) accO[j][p] *= alpha_p[p];

    // P rows: 4 consecutive k per (j,quad) -> packed f16x4 stores (per-warp
    // tile, intra-wave DS ordering, no barrier needed).
#pragma unroll
    for (int j = 0; j < 4; ++j) {
      f16x4 h4, l4;
#pragma unroll
      for (int p = 0; p < 4; ++p) {
        const f16 hi = (f16)s[j][p];
        h4[p] = hi;
        l4[p] = (f16)(s[j][p] - (float)hi);
      }
      const int pc = j * 16 + quad * 4;
      *(f16x4*)&Ph[w][ml * 64 + SWZ(ml, pc)] = h4;
      *(f16x4*)&Pl[w][ml * 64 + SWZ(ml, pc)] = l4;
    }

#pragma unroll
    for (int ks = 0; ks < 2; ++ks) {
      const f16x8 pah = *(const f16x8*)&Ph[w][ml * 64 + SWZ(ml, ks * 32 + quad * 8)];
      const f16x8 pal = *(const f16x8*)&Pl[w][ml * 64 + SWZ(ml, ks * 32 + quad * 8)];
#pragma unroll
      for (int j = 0; j < 4; ++j) {
        const int vr = j * 16 + ml;
        const f16x8 vbh = *(const f16x8*)&Vh[vr * 64 + SWZV(vr, ks * 32 + quad * 8)];
        const f16x8 vbl = *(const f16x8*)&Vl[vr * 64 + SWZV(vr, ks * 32 + quad * 8)];
        accO[j] = __builtin_amdgcn_mfma_f32_16x16x32_f16(pah, vbh, accO[j], 0, 0, 0);
        accO[j] = __builtin_amdgcn_mfma_f32_16x16x32_f16(pah, vbl, accO[j], 0, 0, 0);
        accO[j] = __builtin_amdgcn_mfma_f32_16x16x32_f16(pal, vbh, accO[j], 0, 0, 0);
      }
    }
  }
  float linv_p[4];
  {
    const float linv = 1.0f / l_i;
#pragma unroll
    for (int p = 0; p < 4; ++p) linv_p[p] = __shfl(linv, 20 * quad + p);
  }
  const int trow = q0 + w * 16 + quad * 4;
#pragma unroll
  for (int p = 0; p < 4; ++p) {
    const size_t ob = (size_t)(b * SEQ + trow + p) * 1024 + h * 64 + ml;
#pragma unroll
    for (int j = 0; j < 4; ++j) {
      const float v = accO[j][p] * linv_p[p];
      const f16 hi = (f16)v;
      ogh[ob + j * 16] = hi;
      ogl[ob + j * 16] = (f16)(v - (float)hi);
    }
  }
#undef SWZ
#undef SWZV
}

// ---------------- gate: fp32 logits, softmax, top-2; probs -> workspace ----
__global__ __launch_bounds__(256) void gate_kernel(
    const float* __restrict__ h2, const float* __restrict__ gw,
    int* __restrict__ topi, float* __restrict__ tw, float* __restrict__ me_part) {
  const int tid = threadIdx.x, w = tid >> 6, lane = tid & 63;
  const int t = blockIdx.x * 4 + w;
  const float* xr = h2 + (size_t)t * 1024;
  float acc[8] = {0.f, 0.f, 0.f, 0.f, 0.f, 0.f, 0.f, 0.f};
#pragma unroll
  for (int i = 0; i < 16; ++i) {
    const int d = lane + i * 64;
    const float xv = xr[d];
    const float4 g0 = ((const float4*)(gw + (size_t)d * 8))[0];
    const float4 g1 = ((const float4*)(gw + (size_t)d * 8))[1];
    acc[0] = fmaf(xv, g0.x, acc[0]); acc[1] = fmaf(xv, g0.y, acc[1]);
    acc[2] = fmaf(xv, g0.z, acc[2]); acc[3] = fmaf(xv, g0.w, acc[3]);
    acc[4] = fmaf(xv, g1.x, acc[4]); acc[5] = fmaf(xv, g1.y, acc[5]);
    acc[6] = fmaf(xv, g1.z, acc[6]); acc[7] = fmaf(xv, g1.w, acc[7]);
  }
#pragma unroll
  for (int e = 0; e < 8; ++e) {
    float v = acc[e];
    v += __shfl_xor(v, 1); v += __shfl_xor(v, 2); v += __shfl_xor(v, 4);
    v += __shfl_xor(v, 8); v += __shfl_xor(v, 16); v += __shfl_xor(v, 32);
    acc[e] = v;
  }
  if (lane == 0) {
    float mx = acc[0];
#pragma unroll
    for (int e = 1; e < 8; ++e) mx = fmaxf(mx, acc[e]);
    float ex[8], ssum = 0.f;
#pragma unroll
    for (int e = 0; e < 8; ++e) { ex[e] = __expf(acc[e] - mx); ssum += ex[e]; }
    const float inv = 1.f / ssum;
    float p[8];
#pragma unroll
    for (int e = 0; e < 8; ++e) p[e] = ex[e] * inv;
    int i1 = 0; float v1 = p[0];
#pragma unroll
    for (int e = 1; e < 8; ++e) if (p[e] > v1) { v1 = p[e]; i1 = e; }
    int i2 = (i1 == 0) ? 1 : 0; float v2 = p[i2];
#pragma unroll
    for (int e = 0; e < 8; ++e) if (e != i1 && p[e] > v2) { v2 = p[e]; i2 = e; }
    const float wn = 1.f / (v1 + v2);
    topi[t] = i1; topi[T_TOKENS + t] = i2;
    tw[t] = v1 * wn; tw[T_TOKENS + t] = v2 * wn;
    float4* mp = (float4*)(me_part + (size_t)t * 8);
    mp[0] = make_float4(p[0], p[1], p[2], p[3]);
    mp[1] = make_float4(p[4], p[5], p[6], p[7]);
  }
}

// ---------------- routing: stable per-expert rank + me/aux reduction -------
__global__ __launch_bounds__(256) void route_kernel(
    const int* __restrict__ topi, const float* __restrict__ me_part,
    int* __restrict__ pos, float* __restrict__ aux_out) {
  __shared__ int cnt[256][8];
  __shared__ float fme[256][8];
  __shared__ int tot[8];
  __shared__ float sme[8];
  const int tid = threadIdx.x;
  int lc[8] = {0, 0, 0, 0, 0, 0, 0, 0};
  const int i0 = tid * 32;
  for (int j = 0; j < 32; ++j) lc[topi[i0 + j]]++;
  float fm[8] = {0.f, 0.f, 0.f, 0.f, 0.f, 0.f, 0.f, 0.f};
  for (int r = tid; r < T_TOKENS; r += 256) {
    const float4 p0 = ((const float4*)(me_part + (size_t)r * 8))[0];
    const float4 p1 = ((const float4*)(me_part + (size_t)r * 8))[1];
    fm[0] += p0.x; fm[1] += p0.y; fm[2] += p0.z; fm[3] += p0.w;
    fm[4] += p1.x; fm[5] += p1.y; fm[6] += p1.z; fm[7] += p1.w;
  }
#pragma unroll
  for (int e = 0; e < 8; ++e) { cnt[tid][e] = lc[e]; fme[tid][e] = fm[e]; }
  __syncthreads();
  if (tid < 8) {
    int run = 0;
    float s = 0.f;
    for (int j = 0; j < 256; ++j) {
      const int v = cnt[j][tid];
      cnt[j][tid] = run;
      run += v;
      s += fme[j][tid];
    }
    tot[tid] = run;
    sme[tid] = s;
  }
  __syncthreads();
  int base[8];
#pragma unroll
  for (int e = 0; e < 8; ++e) base[e] = cnt[tid][e];
  for (int j = 0; j < 32; ++j) {
    const int e = topi[i0 + j];
    pos[i0 + j] = base[e]++;
  }
  if (tid == 0) {
    float aux = 0.f;
    for (int e = 0; e < 8; ++e) {
      const float me = sme[e] / 4096.0f;
      const float ce = (float)tot[e] / (4096.0f * 2.0f);
      aux += me * ce;
    }
    aux_out[0] = 8.0f * aux;
  }
}

// ---------------- scatter tokens to expert buffers (bf16) ------------------
__global__ __launch_bounds__(128) void moe_scatter(
    const u16* __restrict__ h2b, const int* __restrict__ topi,
    const int* __restrict__ pos, u16* __restrict__ buf) {
  const int i = blockIdx.x;
  const int p = pos[i];
  if (p >= CAPACITY) return;
  const int e = topi[i];
  const int t = i & (T_TOKENS - 1);
  const uint4* src = (const uint4*)(h2b + (size_t)t * 1024);
  uint4* dst = (uint4*)(buf + ((size_t)e * CAPACITY + p) * 1024);
  dst[threadIdx.x] = src[threadIdx.x];
}

// ---------------- fp32 -> bf16 transposing converter (batched) -------------
__global__ __launch_bounds__(256) void transpose_f32_bf16(
    const float* __restrict__ in, u16* __restrict__ out, int R, int C, long sz) {
  const float* ip = in + (size_t)blockIdx.z * sz;
  u16* op = out + (size_t)blockIdx.z * sz;
  __shared__ float tile[32][33];
  const int c0 = blockIdx.x * 32, r0 = blockIdx.y * 32;
  const int tx = threadIdx.x & 31, ty = threadIdx.x >> 5;
#pragma unroll
  for (int i = 0; i < 32; i += 8)
    tile[ty + i][tx] = ip[(size_t)(r0 + ty + i) * C + c0 + tx];
  __syncthreads();
#pragma unroll
  for (int i = 0; i < 32; i += 8)
    op[(size_t)(c0 + ty + i) * R + r0 + tx] = f2bf(tile[tx][ty + i]);
}

// ------- bf16 MFMA GEMM: C = A[M,K] @ BT[N,K]^T + bias, BK=64 -------------
template <int EPI>
__global__ __launch_bounds__(256, 2) void bgemm_bt(
    const u16* __restrict__ Ab, const u16* __restrict__ BTb,
    const float* __restrict__ biasb, u16* __restrict__ Cb,
    int M, int N, int K, long sA, long sB, long sBias, long sC) {
  const int e = blockIdx.z;
  const u16* A = Ab + (size_t)e * sA;
  const u16* BT = BTb + (size_t)e * sB;
  const float* bias = biasb + (size_t)e * sBias;
  u16* C = Cb + (size_t)e * sC;

  __shared__ u16 As[128 * 72];
  __shared__ u16 Bs[128 * 72];
  const int tid = threadIdx.x, lane = tid & 63, w = tid >> 6;
  const int qd = lane >> 4, ml = lane & 15;
  const int m0 = blockIdx.y * 128, n0 = blockIdx.x * 128;
  const int wm = (w & 1) * 64, wn = (w >> 1) * 64;
  f32x4 acc[4][4] = {};

  const int sr = tid >> 1, sh = (tid & 1) * 32;
  const u16* gA = A + (size_t)(m0 + sr) * K + sh;
  const u16* gB = BT + (size_t)(n0 + sr) * K + sh;
  u16* lA = &As[sr * 72 + sh];
  u16* lB = &Bs[sr * 72 + sh];

  for (int k0 = 0; k0 < K; k0 += 64) {
    uint4 av[4], bv[4];
#pragma unroll
    for (int j = 0; j < 4; ++j) {
      av[j] = *(const uint4*)(gA + k0 + j * 8);
      bv[j] = *(const uint4*)(gB + k0 + j * 8);
    }
    __syncthreads();
#pragma unroll
    for (int j = 0; j < 4; ++j) {
      *(uint4*)(lA + j * 8) = av[j];
      *(uint4*)(lB + j * 8) = bv[j];
    }
    __syncthreads();
#pragma unroll
    for (int kk = 0; kk < 2; ++kk) {
      bf16x8 af[4], bfr[4];
#pragma unroll
      for (int i = 0; i < 4; ++i)
        af[i] = *(const bf16x8*)&As[(wm + i * 16 + ml) * 72 + kk * 32 + qd * 8];
#pragma unroll
      for (int j = 0; j < 4; ++j)
        bfr[j] = *(const bf16x8*)&Bs[(wn + j * 16 + ml) * 72 + kk * 32 + qd * 8];
#pragma unroll
      for (int i = 0; i < 4; ++i)
#pragma unroll
        for (int j = 0; j < 4; ++j)
          acc[i][j] = __builtin_amdgcn_mfma_f32_16x16x32_bf16(af[i], bfr[j], acc[i][j], 0, 0, 0);
    }
  }
#pragma unroll
  for (int i = 0; i < 4; ++i) {
    const int rr = m0 + wm + i * 16 + qd * 4;
#pragma unroll
    for (int j = 0; j < 4; ++j) {
      const int cc = n0 + wn + j * 16 + ml;
      const float bb = bias[cc];
#pragma unroll
      for (int p = 0; p < 4; ++p) {
        float v = acc[i][j][p] + bb;
        if (EPI == 1) v = gelu_f(v);
        C[(size_t)(rr + p) * N + cc] = f2bf(v);
      }
    }
  }
}

// ---------------- gather expert outputs back + final residual add ----------
__global__ __launch_bounds__(256) void moe_gather(
    const u16* __restrict__ outm, const int* __restrict__ topi,
    const int* __restrict__ pos, const float* __restrict__ tw,
    float* __restrict__ y) {
  const int t = blockIdx.x;
  const int d = threadIdx.x * 4;
  float a0 = 0.f, a1 = 0.f, a2 = 0.f, a3 = 0.f;
#pragma unroll
  for (int k = 0; k < 2; ++k) {
    const int i = k * T_TOKENS + t;
    const int p = pos[i];
    if (p < CAPACITY) {
      const int e = topi[i];
      const float wg = tw[i];
      const ushort4 r = *(const ushort4*)(outm + ((size_t)e * CAPACITY + p) * 1024 + d);
      a0 = fmaf(wg, bf2f(r.x), a0);
      a1 = fmaf(wg, bf2f(r.y), a1);
      a2 = fmaf(wg, bf2f(r.z), a2);
      a3 = fmaf(wg, bf2f(r.w), a3);
    }
  }
  float4* op = (float4*)(y + (size_t)t * 1024 + d);
  float4 cur = *op;
  cur.x += a0; cur.y += a1; cur.z += a2; cur.w += a3;
  *op = cur;
}

// ---------------- workspace layout ----------------------------------------
static const size_t OFF_TOPI = 0x100;                    // 8192 i32
static const size_t OFF_TW = 0x8100;                     // 8192 f32
static const size_t OFF_POS = 0x10100;                   // 8192 i32
static const size_t OFF_H = 0x20000;                     // 16MB (h1h/h1l, then oh/ol)
static const size_t OFF_QKV = OFF_H + 0x1000000;         // 48MB (qkvh/qkvl; later outm+h2f)
static const size_t OFF_H2F = OFF_QKV + 0x1400000;       // 16MB f32 (inside qkv region)
static const size_t OFF_H2B = OFF_QKV + 0x3000000;       // 8MB bf16
static const size_t OFF_BUF = OFF_H2B + 0x800000;        // 20MB bf16
static const size_t OFF_WT = OFF_BUF + 0x1400000;        // 64MB (wT f16 / me_part / w1t,w2t)
static const size_t OFF_HH = OFF_WT + 0x4000000;         // 80MB bf16
static const size_t WS_NEED = OFF_HH + 0x5000000;        // ~236 MB

extern "C" void kernel_launch(void* const* d_in, const int* in_sizes, int n_in,
                              void* d_out, int out_size, void* d_ws, size_t ws_size,
                              hipStream_t stream) {
  (void)in_sizes; (void)n_in; (void)out_size;
  if (ws_size < WS_NEED) return;  // fail visibly rather than corrupt

  const float* x = (const float*)d_in[0];
  const float* cosb = (const float*)d_in[1];
  const float* sinb = (const float*)d_in[2];
  const float* ln1g = (const float*)d_in[3];
  const float* ln1b = (const float*)d_in[4];
  const float* ln2g = (const float*)d_in[5];
  const float* ln2b = (const float*)d_in[6];
  const float* wqkv = (const float*)d_in[7];
  const float* bqkv = (const float*)d_in[8];
  const float* wo = (const float*)d_in[9];
  const float* bo = (const float*)d_in[10];
  const float* gatew = (const float*)d_in[11];
  const float* w1 = (const float*)d_in[12];
  const float* b1 = (const float*)d_in[13];
  const float* w2 = (const float*)d_in[14];
  const float* b2 = (const float*)d_in[15];
  float* out = (float*)d_out;

  char* ws = (char*)d_ws;
  int* topi = (int*)(ws + OFF_TOPI);
  float* tw = (float*)(ws + OFF_TW);
  int* pos = (int*)(ws + OFF_POS);
  f16* h1h = (f16*)(ws + OFF_H);                     // 8MB
  f16* h1l = (f16*)(ws + OFF_H + 0x800000);          // 8MB
  f16* oh = h1h;                                     // reuse (h1 dead post-QKV)
  f16* ol = h1l;
  f16* qkvh = (f16*)(ws + OFF_QKV);                  // 24MB
  f16* qkvl = (f16*)(ws + OFF_QKV + 0x1800000);      // 24MB
  u16* outm = (u16*)(ws + OFF_QKV);                  // reuse (qkv dead post-attn)
  float* h2f = (float*)(ws + OFF_H2F);
  u16* h2b = (u16*)(ws + OFF_H2B);
  u16* buf = (u16*)(ws + OFF_BUF);
  u16* wt = (u16*)(ws + OFF_WT);
  f16* wqkvTh = (f16*)(ws + OFF_WT);                 // 6 MB
  f16* wqkvTl = (f16*)(ws + OFF_WT + 0x600000);      // 6 MB
  f16* woTh = (f16*)(ws + OFF_WT + 0xC00000);        // 2 MB
  f16* woTl = (f16*)(ws + OFF_WT + 0xE00000);        // 2 MB
  float* me_part = (float*)(ws + OFF_WT + 0x1000000);
  u16* hh = (u16*)(ws + OFF_HH);

  // pre-gate path: split-fp16 3-pass MFMA (rel err ~2e-7 -> routing exact)
  ln_kernel<<<4096, 256, 0, stream>>>(x, ln1g, ln1b, nullptr, (u16*)nullptr, h1h, h1l);
  transpose_f32_f16hl<<<dim3(96, 32), 256, 0, stream>>>(wqkv, wqkvTh, wqkvTl, 1024, 3072);
  gemm_f16x3_bt<0><<<dim3(24, 32), 256, 0, stream>>>(h1h, h1l, wqkvTh, wqkvTl, bqkv,
                                                     nullptr, nullptr, qkvh, qkvl,
                                                     4096, 3072, 1024);
  rope_kernel<<<4096, 256, 0, stream>>>(qkvh, qkvl, cosb, sinb);
  transpose_f32_f16hl<<<dim3(32, 32), 256, 0, stream>>>(wo, woTh, woTl, 1024, 1024);
  attn_mfma<<<dim3(32, 32), 256, 0, stream>>>(qkvh, qkvl, oh, ol);
  gemm_f16x3_bt<1><<<dim3(8, 32), 256, 0, stream>>>(oh, ol, woTh, woTl, bo, x,
                                                    out, nullptr, nullptr,
                                                    4096, 1024, 1024);
  ln_kernel<<<4096, 256, 0, stream>>>(out, ln2g, ln2b, h2f, h2b, nullptr, nullptr);
  gate_kernel<<<1024, 256, 0, stream>>>(h2f, gatew, topi, tw, me_part);
  route_kernel<<<1, 256, 0, stream>>>(topi, me_part, pos, out + 4194304);

  // MoE experts: bf16 MFMA (smooth path). No buf memset needed: capacity
  // rows beyond each expert's count are row-independent through both GEMMs
  // and never touched by gather (pos < CAPACITY guard covers exactly the
  // rows scatter wrote).
  moe_scatter<<<8192, 128, 0, stream>>>(h2b, topi, pos, buf);
  transpose_f32_bf16<<<dim3(128, 32, 8), 256, 0, stream>>>(w1, wt, 1024, 4096, 1024L * 4096);
  bgemm_bt<1><<<dim3(32, 10, 8), 256, 0, stream>>>(buf, wt, b1, hh, 1280, 4096, 1024,
                                                   1280L * 1024, 4096L * 1024, 4096, 1280L * 4096);
  transpose_f32_bf16<<<dim3(32, 128, 8), 256, 0, stream>>>(w2, wt, 4096, 1024, 4096L * 1024);
  bgemm_bt<0><<<dim3(8, 10, 8), 256, 0, stream>>>(hh, wt, b2, outm, 1280, 1024, 4096,
                                                  1280L * 4096, 1024L * 4096, 1024, 1280L * 1024);
  moe_gather<<<4096, 256, 0, stream>>>(outm, topi, pos, tw, out);
}

// Round 9
// 1035.655 us; speedup vs baseline: 1.9046x; 1.9046x over previous
//
#include <hip/hip_runtime.h>

// Round 8 (2nd submit; prior attempt hit GPU-acquisition timeout, no data).
// Revert R7's BK=64 bgemm regression (689us/dispatch, 15x write
// amplification ~ scratch round-trip of the doubled staging registers live
// across the barrier) -> exact R5 BK=32 bgemm (measured-good). Keep ONE
// attn change vs R5: V tiles swizzle with H(r)=(r^(r>>2))&7 (R6 proved
// conflicts live in V-transpose writes; rows stride 4 so (r&7) spans only
// 2 values -> 8 with the new hash). Everything else byte-identical to R5
// (measured 1036.6us, attn 239us, conflicts 3.355e7).

typedef unsigned short u16;
typedef short bf16x8 __attribute__((ext_vector_type(8)));
typedef float f32x4 __attribute__((ext_vector_type(4)));
typedef _Float16 f16;
typedef f16 f16x8 __attribute__((ext_vector_type(8)));
typedef f16 f16x4 __attribute__((ext_vector_type(4)));
typedef f16 f16x2 __attribute__((ext_vector_type(2)));

#define T_TOKENS 4096
#define SEQ      2048
#define CAPACITY 1280

__device__ __forceinline__ u16 f2bf(float f) {
  unsigned int u = __float_as_uint(f);
  return (u16)((u + 0x7FFFu + ((u >> 16) & 1u)) >> 16);
}
__device__ __forceinline__ float bf2f(u16 h) {
  return __uint_as_float(((unsigned int)h) << 16);
}
__device__ __forceinline__ float gelu_f(float x) {
  float x3 = x * x * x;
  float t = tanhf(0.7978845608028654f * (x + 0.044715f * x3));
  return 0.5f * x * (1.0f + t);
}

// ---------------- LayerNorm (fp32 in; f32 / bf16 / split-f16 out) ----------
__global__ __launch_bounds__(256) void ln_kernel(
    const float* __restrict__ x, const float* __restrict__ g,
    const float* __restrict__ bt, float* __restrict__ of32,
    u16* __restrict__ obf, f16* __restrict__ oh, f16* __restrict__ ol) {
  const int t = blockIdx.x, tid = threadIdx.x;
  float4 v = ((const float4*)(x + (size_t)t * 1024))[tid];
  float s = v.x + v.y + v.z + v.w;
  float sq = v.x * v.x + v.y * v.y + v.z * v.z + v.w * v.w;
#pragma unroll
  for (int d = 1; d < 64; d <<= 1) {
    s += __shfl_xor(s, d);
    sq += __shfl_xor(sq, d);
  }
  __shared__ float red[8];
  if ((tid & 63) == 0) { red[tid >> 6] = s; red[4 + (tid >> 6)] = sq; }
  __syncthreads();
  s = red[0] + red[1] + red[2] + red[3];
  sq = red[4] + red[5] + red[6] + red[7];
  const float mu = s * (1.0f / 1024.0f);
  const float var = sq * (1.0f / 1024.0f) - mu * mu;
  const float rs = rsqrtf(var + 1e-6f);
  float4 gv = ((const float4*)g)[tid];
  float4 bv = ((const float4*)bt)[tid];
  float4 o;
  o.x = (v.x - mu) * rs * gv.x + bv.x;
  o.y = (v.y - mu) * rs * gv.y + bv.y;
  o.z = (v.z - mu) * rs * gv.z + bv.z;
  o.w = (v.w - mu) * rs * gv.w + bv.w;
  if (of32) ((float4*)(of32 + (size_t)t * 1024))[tid] = o;
  if (obf) {
    ushort4 ob;
    ob.x = f2bf(o.x); ob.y = f2bf(o.y); ob.z = f2bf(o.z); ob.w = f2bf(o.w);
    ((ushort4*)(obf + (size_t)t * 1024))[tid] = ob;
  }
  if (oh) {
    const float f[4] = {o.x, o.y, o.z, o.w};
    f16x4 hv, lv;
#pragma unroll
    for (int i = 0; i < 4; ++i) {
      f16 hi = (f16)f[i];
      hv[i] = hi;
      lv[i] = (f16)(f[i] - (float)hi);
    }
    ((f16x4*)(oh + (size_t)t * 1024))[tid] = hv;
    ((f16x4*)(ol + (size_t)t * 1024))[tid] = lv;
  }
}

// ------- transpose fp32 [R][C] -> f16 hi/lo [C][R] (weight prep) ----------
__global__ __launch_bounds__(256) void transpose_f32_f16hl(
    const float* __restrict__ in, f16* __restrict__ outh, f16* __restrict__ outl,
    int R, int C) {
  __shared__ float tile[32][33];
  const int c0 = blockIdx.x * 32, r0 = blockIdx.y * 32;
  const int tx = threadIdx.x & 31, ty = threadIdx.x >> 5;
#pragma unroll
  for (int i = 0; i < 32; i += 8)
    tile[ty + i][tx] = in[(size_t)(r0 + ty + i) * C + c0 + tx];
  __syncthreads();
#pragma unroll
  for (int i = 0; i < 32; i += 8) {
    const float v = tile[tx][ty + i];
    const f16 hi = (f16)v;
    const size_t idx = (size_t)(c0 + ty + i) * R + r0 + tx;
    outh[idx] = hi;
    outl[idx] = (f16)(v - (float)hi);
  }
}

// ------- split-fp16 3-pass MFMA GEMM, pre-split A planes -------------------
// EPI=0: write split-f16 C planes (Ch/Cl). EPI=1: write f32 C (+res).
template <int EPI>
__global__ __launch_bounds__(256, 2) void gemm_f16x3_bt(
    const f16* __restrict__ Agh, const f16* __restrict__ Agl,
    const f16* __restrict__ Bth, const f16* __restrict__ Btl,
    const float* __restrict__ bias, const float* __restrict__ res,
    float* __restrict__ C, f16* __restrict__ Ch, f16* __restrict__ Cl,
    int M, int N, int K) {
  __shared__ f16 Ah[128 * 40], Al[128 * 40], Bh[128 * 40], Bl[128 * 40];
  const int tid = threadIdx.x, lane = tid & 63, w = tid >> 6;
  const int qd = lane >> 4, ml = lane & 15;
  const int m0 = blockIdx.y * 128, n0 = blockIdx.x * 128;
  const int wm = (w & 1) * 64, wn = (w >> 1) * 64;
  f32x4 acc[4][4] = {};

  const int sr = tid >> 1, sc = (tid & 1) * 16;
  const f16* gAh = Agh + (size_t)(m0 + sr) * K + sc;
  const f16* gAl = Agl + (size_t)(m0 + sr) * K + sc;
  const f16* gBh = Bth + (size_t)(n0 + sr) * K + sc;
  const f16* gBl = Btl + (size_t)(n0 + sr) * K + sc;
  f16* lAh = &Ah[sr * 40 + sc];
  f16* lAl = &Al[sr * 40 + sc];
  f16* lBh = &Bh[sr * 40 + sc];
  f16* lBl = &Bl[sr * 40 + sc];

  for (int k0 = 0; k0 < K; k0 += 32) {
    const uint4 ah0 = *(const uint4*)(gAh + k0);
    const uint4 ah1 = *(const uint4*)(gAh + k0 + 8);
    const uint4 al0 = *(const uint4*)(gAl + k0);
    const uint4 al1 = *(const uint4*)(gAl + k0 + 8);
    const uint4 bh0 = *(const uint4*)(gBh + k0);
    const uint4 bh1 = *(const uint4*)(gBh + k0 + 8);
    const uint4 bl0 = *(const uint4*)(gBl + k0);
    const uint4 bl1 = *(const uint4*)(gBl + k0 + 8);
    __syncthreads();
    *(uint4*)lAh = ah0; *(uint4*)(lAh + 8) = ah1;
    *(uint4*)lAl = al0; *(uint4*)(lAl + 8) = al1;
    *(uint4*)lBh = bh0; *(uint4*)(lBh + 8) = bh1;
    *(uint4*)lBl = bl0; *(uint4*)(lBl + 8) = bl1;
    __syncthreads();
    f16x8 fah[4], fal[4], fbh[4], fbl[4];
#pragma unroll
    for (int i = 0; i < 4; ++i) {
      fah[i] = *(const f16x8*)&Ah[(wm + i * 16 + ml) * 40 + qd * 8];
      fal[i] = *(const f16x8*)&Al[(wm + i * 16 + ml) * 40 + qd * 8];
    }
#pragma unroll
    for (int j = 0; j < 4; ++j) {
      fbh[j] = *(const f16x8*)&Bh[(wn + j * 16 + ml) * 40 + qd * 8];
      fbl[j] = *(const f16x8*)&Bl[(wn + j * 16 + ml) * 40 + qd * 8];
    }
#pragma unroll
    for (int i = 0; i < 4; ++i)
#pragma unroll
      for (int j = 0; j < 4; ++j) {
        acc[i][j] = __builtin_amdgcn_mfma_f32_16x16x32_f16(fah[i], fbh[j], acc[i][j], 0, 0, 0);
        acc[i][j] = __builtin_amdgcn_mfma_f32_16x16x32_f16(fah[i], fbl[j], acc[i][j], 0, 0, 0);
        acc[i][j] = __builtin_amdgcn_mfma_f32_16x16x32_f16(fal[i], fbh[j], acc[i][j], 0, 0, 0);
      }
  }
#pragma unroll
  for (int i = 0; i < 4; ++i) {
    const int rr = m0 + wm + i * 16 + qd * 4;
#pragma unroll
    for (int j = 0; j < 4; ++j) {
      const int cc = n0 + wn + j * 16 + ml;
      const float bb = bias[cc];
#pragma unroll
      for (int p = 0; p < 4; ++p) {
        float v = acc[i][j][p] + bb;
        const size_t idx = (size_t)(rr + p) * N + cc;
        if (EPI == 1) {
          C[idx] = v + res[idx];
        } else {
          const f16 hi = (f16)v;
          Ch[idx] = hi;
          Cl[idx] = (f16)(v - (float)hi);
        }
      }
    }
  }
}

// ---------------- RoPE (in-place on split-f16 qkv planes, q scaled 1/8) ----
__global__ __launch_bounds__(256) void rope_kernel(
    f16* __restrict__ qh, f16* __restrict__ ql, const float* __restrict__ cosb,
    const float* __restrict__ sinb) {
  const int t = blockIdx.x;
  const int s = t & (SEQ - 1);
  f16* rh = qh + (size_t)t * 3072;
  f16* rl = ql + (size_t)t * 3072;
  const int tid = threadIdx.x;
#pragma unroll
  for (int it = 0; it < 2; ++it) {
    const int p = tid + it * 256;            // 512 pair-pairs (q,k sections)
    const int sec = p >> 8;                  // 0=q, 1=k
    const int rem = p & 255;
    const int hd = rem >> 4, d = (rem & 15) * 2;
    const int col = sec * 1024 + hd * 64 + d;
    const float c1a = cosb[s * 64 + d], s1a = sinb[s * 64 + d];
    const float c1b = cosb[s * 64 + d + 1], s1b = sinb[s * 64 + d + 1];
    const float c2a = cosb[s * 64 + d + 32], s2a = sinb[s * 64 + d + 32];
    const float c2b = cosb[s * 64 + d + 33], s2b = sinb[s * 64 + d + 33];
    const f16x2 ah = *(const f16x2*)(rh + col);
    const f16x2 al = *(const f16x2*)(rl + col);
    const f16x2 bh = *(const f16x2*)(rh + col + 32);
    const f16x2 bl = *(const f16x2*)(rl + col + 32);
    const float a0 = (float)ah[0] + (float)al[0];
    const float a1 = (float)ah[1] + (float)al[1];
    const float b0 = (float)bh[0] + (float)bl[0];
    const float b1 = (float)bh[1] + (float)bl[1];
    float na0 = a0 * c1a - b0 * s1a;
    float na1 = a1 * c1b - b1 * s1b;
    float nb0 = b0 * c2a + a0 * s2a;
    float nb1 = b1 * c2b + a1 * s2b;
    if (sec == 0) { na0 *= 0.125f; na1 *= 0.125f; nb0 *= 0.125f; nb1 *= 0.125f; }
    f16x2 nah, nal, nbh, nbl;
    nah[0] = (f16)na0; nal[0] = (f16)(na0 - (float)nah[0]);
    nah[1] = (f16)na1; nal[1] = (f16)(na1 - (float)nah[1]);
    nbh[0] = (f16)nb0; nbl[0] = (f16)(nb0 - (float)nbh[0]);
    nbh[1] = (f16)nb1; nbl[1] = (f16)(nb1 - (float)nbh[1]);
    *(f16x2*)(rh + col) = nah;
    *(f16x2*)(rl + col) = nal;
    *(f16x2*)(rh + col + 32) = nbh;
    *(f16x2*)(rl + col + 32) = nbl;
  }
}

// ---------------- split-fp16 MFMA flash attention (swapped QK^T) -----------
__global__ __launch_bounds__(256) void attn_mfma(
    const f16* __restrict__ qkvh, const f16* __restrict__ qkvl,
    f16* __restrict__ ogh, f16* __restrict__ ogl) {
  const int bh_ = blockIdx.y, b = bh_ >> 4, h = bh_ & 15;
  const int tid = threadIdx.x, w = tid >> 6, lane = tid & 63;
  const int quad = lane >> 4, ml = lane & 15;
  const int q0 = blockIdx.x * 64;
  const f16* baseh = qkvh + (size_t)b * SEQ * 3072 + h * 64;
  const f16* basel = qkvl + (size_t)b * SEQ * 3072 + h * 64;

  // Unpadded [64][64] tiles, 16B-granular XOR swizzles. K/P rows are
  // lane-stride-1 -> (r&7) spreads fine. V rows are lane-stride-4
  // (vr=4ml+dd) -> (r&7) spans only 2 values (R6 counter evidence);
  // (r^(r>>2))&7 spans 8 on both vr=4ml+dd and vr=16j+ml.
  __shared__ f16 Kh[64 * 64], Kl[64 * 64];     // [key][d]
  __shared__ f16 Vh[64 * 64], Vl[64 * 64];     // [d][key]
  __shared__ f16 Ph[4][16 * 64], Pl[4][16 * 64];  // per-warp [q][key]

#define SWZ(r, c) ((c) ^ (((r) & 7) << 3))
#define SWZV(r, c) ((c) ^ ((((r) ^ ((r) >> 2)) & 7) << 3))

  f16x8 qh[2], ql[2];
  {
    const f16* qrh = baseh + (size_t)(q0 + w * 16 + ml) * 3072;
    const f16* qrl = basel + (size_t)(q0 + w * 16 + ml) * 3072;
#pragma unroll
    for (int ks = 0; ks < 2; ++ks) {
      qh[ks] = *(const f16x8*)(qrh + ks * 32 + quad * 8);
      ql[ks] = *(const f16x8*)(qrl + ks * 32 + quad * 8);
    }
  }

  float m_i = -1e30f, l_i = 0.f;   // online stats for q-row = q0+w*16+ml
  f32x4 accO[4] = {};

  const int skey = tid >> 2, scg = (tid & 3) * 16;
  const int sd0 = (tid & 15) * 4, sk0 = (tid >> 4) * 4;

  for (int c0 = 0; c0 < SEQ; c0 += 64) {
    __syncthreads();
    {
      const f16* krh = baseh + 1024 + (size_t)(c0 + skey) * 3072 + scg;
      const f16* krl = basel + 1024 + (size_t)(c0 + skey) * 3072 + scg;
      *(f16x8*)&Kh[skey * 64 + SWZ(skey, scg)] = *(const f16x8*)krh;
      *(f16x8*)&Kh[skey * 64 + SWZ(skey, scg + 8)] = *(const f16x8*)(krh + 8);
      *(f16x8*)&Kl[skey * 64 + SWZ(skey, scg)] = *(const f16x8*)krl;
      *(f16x8*)&Kl[skey * 64 + SWZ(skey, scg + 8)] = *(const f16x8*)(krl + 8);

      f16x4 rvh[4], rvl[4];
#pragma unroll
      for (int i = 0; i < 4; ++i) {
        rvh[i] = *(const f16x4*)(baseh + 2048 + (size_t)(c0 + sk0 + i) * 3072 + sd0);
        rvl[i] = *(const f16x4*)(basel + 2048 + (size_t)(c0 + sk0 + i) * 3072 + sd0);
      }
#pragma unroll
      for (int dd = 0; dd < 4; ++dd) {
        f16x4 vh4, vl4;
#pragma unroll
        for (int i = 0; i < 4; ++i) { vh4[i] = rvh[i][dd]; vl4[i] = rvl[i][dd]; }
        const int vr = sd0 + dd;
        *(f16x4*)&Vh[vr * 64 + SWZV(vr, sk0)] = vh4;
        *(f16x4*)&Vl[vr * 64 + SWZV(vr, sk0)] = vl4;
      }
    }
    __syncthreads();

    // Swapped QK^T: s[j][p] = S^T[k = 16j+4*quad+p][q = ml].
    f32x4 s[4] = {};
#pragma unroll
    for (int ks = 0; ks < 2; ++ks)
#pragma unroll
      for (int j = 0; j < 4; ++j) {
        const int kr = j * 16 + ml;
        const f16x8 kh = *(const f16x8*)&Kh[kr * 64 + SWZ(kr, ks * 32 + quad * 8)];
        const f16x8 kl = *(const f16x8*)&Kl[kr * 64 + SWZ(kr, ks * 32 + quad * 8)];
        s[j] = __builtin_amdgcn_mfma_f32_16x16x32_f16(kh, qh[ks], s[j], 0, 0, 0);
        s[j] = __builtin_amdgcn_mfma_f32_16x16x32_f16(kl, qh[ks], s[j], 0, 0, 0);
        s[j] = __builtin_amdgcn_mfma_f32_16x16x32_f16(kh, ql[ks], s[j], 0, 0, 0);
      }

    // Online softmax: one q per lane -> scalar stats, 2 shfl per reduce.
    float pmax = s[0][0];
#pragma unroll
    for (int j = 0; j < 4; ++j)
#pragma unroll
      for (int p = 0; p < 4; ++p) pmax = fmaxf(pmax, s[j][p]);
    pmax = fmaxf(pmax, __shfl_xor(pmax, 16));
    pmax = fmaxf(pmax, __shfl_xor(pmax, 32));
    const float mn = fmaxf(m_i, pmax);
    const float al = __expf(m_i - mn);
    float rs = 0.f;
#pragma unroll
    for (int j = 0; j < 4; ++j)
#pragma unroll
      for (int p = 0; p < 4; ++p) {
        const float e = __expf(s[j][p] - mn);
        s[j][p] = e;
        rs += e;
      }
    rs += __shfl_xor(rs, 16);
    rs += __shfl_xor(rs, 32);
    m_i = mn;
    l_i = l_i * al + rs;

    // alpha lives at lane(q=ml); accO needs it at q=4*quad+p.
    float alpha_p[4];
#pragma unroll
    for (int p = 0; p < 4; ++p) alpha_p[p] = __shfl(al, 20 * quad + p);
#pragma unroll
    for (int j = 0; j < 4; ++j)
#pragma unroll
      for (int p = 0; p < 4; ++p) accO[j][p] *= alpha_p[p];

    // P rows: 4 consecutive k per (j,quad) -> packed f16x4 stores (per-warp
    // tile, intra-wave DS ordering, no barrier needed).
#pragma unroll
    for (int j = 0; j < 4; ++j) {
      f16x4 h4, l4;
#pragma unroll
      for (int p = 0; p < 4; ++p) {
        const f16 hi = (f16)s[j][p];
        h4[p] = hi;
        l4[p] = (f16)(s[j][p] - (float)hi);
      }
      const int pc = j * 16 + quad * 4;
      *(f16x4*)&Ph[w][ml * 64 + SWZ(ml, pc)] = h4;
      *(f16x4*)&Pl[w][ml * 64 + SWZ(ml, pc)] = l4;
    }

#pragma unroll
    for (int ks = 0; ks < 2; ++ks) {
      const f16x8 pah = *(const f16x8*)&Ph[w][ml * 64 + SWZ(ml, ks * 32 + quad * 8)];
      const f16x8 pal = *(const f16x8*)&Pl[w][ml * 64 + SWZ(ml, ks * 32 + quad * 8)];
#pragma unroll
      for (int j = 0; j < 4; ++j) {
        const int vr = j * 16 + ml;
        const f16x8 vbh = *(const f16x8*)&Vh[vr * 64 + SWZV(vr, ks * 32 + quad * 8)];
        const f16x8 vbl = *(const f16x8*)&Vl[vr * 64 + SWZV(vr, ks * 32 + quad * 8)];
        accO[j] = __builtin_amdgcn_mfma_f32_16x16x32_f16(pah, vbh, accO[j], 0, 0, 0);
        accO[j] = __builtin_amdgcn_mfma_f32_16x16x32_f16(pah, vbl, accO[j], 0, 0, 0);
        accO[j] = __builtin_amdgcn_mfma_f32_16x16x32_f16(pal, vbh, accO[j], 0, 0, 0);
      }
    }
  }
  float linv_p[4];
  {
    const float linv = 1.0f / l_i;
#pragma unroll
    for (int p = 0; p < 4; ++p) linv_p[p] = __shfl(linv, 20 * quad + p);
  }
  const int trow = q0 + w * 16 + quad * 4;
#pragma unroll
  for (int p = 0; p < 4; ++p) {
    const size_t ob = (size_t)(b * SEQ + trow + p) * 1024 + h * 64 + ml;
#pragma unroll
    for (int j = 0; j < 4; ++j) {
      const float v = accO[j][p] * linv_p[p];
      const f16 hi = (f16)v;
      ogh[ob + j * 16] = hi;
      ogl[ob + j * 16] = (f16)(v - (float)hi);
    }
  }
#undef SWZ
#undef SWZV
}

// ---------------- gate: fp32 logits, softmax, top-2; probs -> workspace ----
__global__ __launch_bounds__(256) void gate_kernel(
    const float* __restrict__ h2, const float* __restrict__ gw,
    int* __restrict__ topi, float* __restrict__ tw, float* __restrict__ me_part) {
  const int tid = threadIdx.x, w = tid >> 6, lane = tid & 63;
  const int t = blockIdx.x * 4 + w;
  const float* xr = h2 + (size_t)t * 1024;
  float acc[8] = {0.f, 0.f, 0.f, 0.f, 0.f, 0.f, 0.f, 0.f};
#pragma unroll
  for (int i = 0; i < 16; ++i) {
    const int d = lane + i * 64;
    const float xv = xr[d];
    const float4 g0 = ((const float4*)(gw + (size_t)d * 8))[0];
    const float4 g1 = ((const float4*)(gw + (size_t)d * 8))[1];
    acc[0] = fmaf(xv, g0.x, acc[0]); acc[1] = fmaf(xv, g0.y, acc[1]);
    acc[2] = fmaf(xv, g0.z, acc[2]); acc[3] = fmaf(xv, g0.w, acc[3]);
    acc[4] = fmaf(xv, g1.x, acc[4]); acc[5] = fmaf(xv, g1.y, acc[5]);
    acc[6] = fmaf(xv, g1.z, acc[6]); acc[7] = fmaf(xv, g1.w, acc[7]);
  }
#pragma unroll
  for (int e = 0; e < 8; ++e) {
    float v = acc[e];
    v += __shfl_xor(v, 1); v += __shfl_xor(v, 2); v += __shfl_xor(v, 4);
    v += __shfl_xor(v, 8); v += __shfl_xor(v, 16); v += __shfl_xor(v, 32);
    acc[e] = v;
  }
  if (lane == 0) {
    float mx = acc[0];
#pragma unroll
    for (int e = 1; e < 8; ++e) mx = fmaxf(mx, acc[e]);
    float ex[8], ssum = 0.f;
#pragma unroll
    for (int e = 0; e < 8; ++e) { ex[e] = __expf(acc[e] - mx); ssum += ex[e]; }
    const float inv = 1.f / ssum;
    float p[8];
#pragma unroll
    for (int e = 0; e < 8; ++e) p[e] = ex[e] * inv;
    int i1 = 0; float v1 = p[0];
#pragma unroll
    for (int e = 1; e < 8; ++e) if (p[e] > v1) { v1 = p[e]; i1 = e; }
    int i2 = (i1 == 0) ? 1 : 0; float v2 = p[i2];
#pragma unroll
    for (int e = 0; e < 8; ++e) if (e != i1 && p[e] > v2) { v2 = p[e]; i2 = e; }
    const float wn = 1.f / (v1 + v2);
    topi[t] = i1; topi[T_TOKENS + t] = i2;
    tw[t] = v1 * wn; tw[T_TOKENS + t] = v2 * wn;
    float4* mp = (float4*)(me_part + (size_t)t * 8);
    mp[0] = make_float4(p[0], p[1], p[2], p[3]);
    mp[1] = make_float4(p[4], p[5], p[6], p[7]);
  }
}

// ---------------- routing: stable per-expert rank + me/aux reduction -------
__global__ __launch_bounds__(256) void route_kernel(
    const int* __restrict__ topi, const float* __restrict__ me_part,
    int* __restrict__ pos, float* __restrict__ aux_out) {
  __shared__ int cnt[256][8];
  __shared__ float fme[256][8];
  __shared__ int tot[8];
  __shared__ float sme[8];
  const int tid = threadIdx.x;
  int lc[8] = {0, 0, 0, 0, 0, 0, 0, 0};
  const int i0 = tid * 32;
  for (int j = 0; j < 32; ++j) lc[topi[i0 + j]]++;
  float fm[8] = {0.f, 0.f, 0.f, 0.f, 0.f, 0.f, 0.f, 0.f};
  for (int r = tid; r < T_TOKENS; r += 256) {
    const float4 p0 = ((const float4*)(me_part + (size_t)r * 8))[0];
    const float4 p1 = ((const float4*)(me_part + (size_t)r * 8))[1];
    fm[0] += p0.x; fm[1] += p0.y; fm[2] += p0.z; fm[3] += p0.w;
    fm[4] += p1.x; fm[5] += p1.y; fm[6] += p1.z; fm[7] += p1.w;
  }
#pragma unroll
  for (int e = 0; e < 8; ++e) { cnt[tid][e] = lc[e]; fme[tid][e] = fm[e]; }
  __syncthreads();
  if (tid < 8) {
    int run = 0;
    float s = 0.f;
    for (int j = 0; j < 256; ++j) {
      const int v = cnt[j][tid];
      cnt[j][tid] = run;
      run += v;
      s += fme[j][tid];
    }
    tot[tid] = run;
    sme[tid] = s;
  }
  __syncthreads();
  int base[8];
#pragma unroll
  for (int e = 0; e < 8; ++e) base[e] = cnt[tid][e];
  for (int j = 0; j < 32; ++j) {
    const int e = topi[i0 + j];
    pos[i0 + j] = base[e]++;
  }
  if (tid == 0) {
    float aux = 0.f;
    for (int e = 0; e < 8; ++e) {
      const float me = sme[e] / 4096.0f;
      const float ce = (float)tot[e] / (4096.0f * 2.0f);
      aux += me * ce;
    }
    aux_out[0] = 8.0f * aux;
  }
}

// ---------------- scatter tokens to expert buffers (bf16) ------------------
__global__ __launch_bounds__(128) void moe_scatter(
    const u16* __restrict__ h2b, const int* __restrict__ topi,
    const int* __restrict__ pos, u16* __restrict__ buf) {
  const int i = blockIdx.x;
  const int p = pos[i];
  if (p >= CAPACITY) return;
  const int e = topi[i];
  const int t = i & (T_TOKENS - 1);
  const uint4* src = (const uint4*)(h2b + (size_t)t * 1024);
  uint4* dst = (uint4*)(buf + ((size_t)e * CAPACITY + p) * 1024);
  dst[threadIdx.x] = src[threadIdx.x];
}

// ---------------- fp32 -> bf16 transposing converter (batched) -------------
__global__ __launch_bounds__(256) void transpose_f32_bf16(
    const float* __restrict__ in, u16* __restrict__ out, int R, int C, long sz) {
  const float* ip = in + (size_t)blockIdx.z * sz;
  u16* op = out + (size_t)blockIdx.z * sz;
  __shared__ float tile[32][33];
  const int c0 = blockIdx.x * 32, r0 = blockIdx.y * 32;
  const int tx = threadIdx.x & 31, ty = threadIdx.x >> 5;
#pragma unroll
  for (int i = 0; i < 32; i += 8)
    tile[ty + i][tx] = ip[(size_t)(r0 + ty + i) * C + c0 + tx];
  __syncthreads();
#pragma unroll
  for (int i = 0; i < 32; i += 8)
    op[(size_t)(c0 + ty + i) * R + r0 + tx] = f2bf(tile[tx][ty + i]);
}

// ---------------- bf16 MFMA GEMM: C = A[M,K] @ BT[N,K]^T + bias ------------
template <int EPI>
__global__ __launch_bounds__(256, 2) void bgemm_bt(
    const u16* __restrict__ Ab, const u16* __restrict__ BTb,
    const float* __restrict__ biasb, u16* __restrict__ Cb,
    int M, int N, int K, long sA, long sB, long sBias, long sC) {
  const int e = blockIdx.z;
  const u16* A = Ab + (size_t)e * sA;
  const u16* BT = BTb + (size_t)e * sB;
  const float* bias = biasb + (size_t)e * sBias;
  u16* C = Cb + (size_t)e * sC;

  __shared__ u16 As[128 * 40];
  __shared__ u16 Bs[128 * 40];
  const int tid = threadIdx.x, lane = tid & 63, w = tid >> 6;
  const int qd = lane >> 4, ml = lane & 15;
  const int m0 = blockIdx.y * 128, n0 = blockIdx.x * 128;
  const int wm = (w & 1) * 64, wn = (w >> 1) * 64;
  f32x4 acc[4][4] = {};

  const int sr = tid >> 1, sh = (tid & 1) * 16;
  const u16* gA = A + (size_t)(m0 + sr) * K + sh;
  const u16* gB = BT + (size_t)(n0 + sr) * K + sh;
  u16* lA = &As[sr * 40 + sh];
  u16* lB = &Bs[sr * 40 + sh];

  for (int k0 = 0; k0 < K; k0 += 32) {
    const uint4 av0 = *(const uint4*)(gA + k0);
    const uint4 av1 = *(const uint4*)(gA + k0 + 8);
    const uint4 bv0 = *(const uint4*)(gB + k0);
    const uint4 bv1 = *(const uint4*)(gB + k0 + 8);
    __syncthreads();
    *(uint4*)lA = av0; *(uint4*)(lA + 8) = av1;
    *(uint4*)lB = bv0; *(uint4*)(lB + 8) = bv1;
    __syncthreads();
    bf16x8 af[4], bfr[4];
#pragma unroll
    for (int i = 0; i < 4; ++i)
      af[i] = *(const bf16x8*)&As[(wm + i * 16 + ml) * 40 + qd * 8];
#pragma unroll
    for (int j = 0; j < 4; ++j)
      bfr[j] = *(const bf16x8*)&Bs[(wn + j * 16 + ml) * 40 + qd * 8];
#pragma unroll
    for (int i = 0; i < 4; ++i)
#pragma unroll
      for (int j = 0; j < 4; ++j)
        acc[i][j] = __builtin_amdgcn_mfma_f32_16x16x32_bf16(af[i], bfr[j], acc[i][j], 0, 0, 0);
  }
#pragma unroll
  for (int i = 0; i < 4; ++i) {
    const int rr = m0 + wm + i * 16 + qd * 4;
#pragma unroll
    for (int j = 0; j < 4; ++j) {
      const int cc = n0 + wn + j * 16 + ml;
      const float bb = bias[cc];
#pragma unroll
      for (int p = 0; p < 4; ++p) {
        float v = acc[i][j][p] + bb;
        if (EPI == 1) v = gelu_f(v);
        C[(size_t)(rr + p) * N + cc] = f2bf(v);
      }
    }
  }
}

// ---------------- gather expert outputs back + final residual add ----------
__global__ __launch_bounds__(256) void moe_gather(
    const u16* __restrict__ outm, const int* __restrict__ topi,
    const int* __restrict__ pos, const float* __restrict__ tw,
    float* __restrict__ y) {
  const int t = blockIdx.x;
  const int d = threadIdx.x * 4;
  float a0 = 0.f, a1 = 0.f, a2 = 0.f, a3 = 0.f;
#pragma unroll
  for (int k = 0; k < 2; ++k) {
    const int i = k * T_TOKENS + t;
    const int p = pos[i];
    if (p < CAPACITY) {
      const int e = topi[i];
      const float wg = tw[i];
      const ushort4 r = *(const ushort4*)(outm + ((size_t)e * CAPACITY + p) * 1024 + d);
      a0 = fmaf(wg, bf2f(r.x), a0);
      a1 = fmaf(wg, bf2f(r.y), a1);
      a2 = fmaf(wg, bf2f(r.z), a2);
      a3 = fmaf(wg, bf2f(r.w), a3);
    }
  }
  float4* op = (float4*)(y + (size_t)t * 1024 + d);
  float4 cur = *op;
  cur.x += a0; cur.y += a1; cur.z += a2; cur.w += a3;
  *op = cur;
}

// ---------------- workspace layout ----------------------------------------
static const size_t OFF_TOPI = 0x100;                    // 8192 i32
static const size_t OFF_TW = 0x8100;                     // 8192 f32
static const size_t OFF_POS = 0x10100;                   // 8192 i32
static const size_t OFF_H = 0x20000;                     // 16MB (h1h/h1l, then oh/ol)
static const size_t OFF_QKV = OFF_H + 0x1000000;         // 48MB (qkvh/qkvl; later outm+h2f)
static const size_t OFF_H2F = OFF_QKV + 0x1400000;       // 16MB f32 (inside qkv region)
static const size_t OFF_H2B = OFF_QKV + 0x3000000;       // 8MB bf16
static const size_t OFF_BUF = OFF_H2B + 0x800000;        // 20MB bf16
static const size_t OFF_WT = OFF_BUF + 0x1400000;        // 64MB (wT f16 / me_part / w1t,w2t)
static const size_t OFF_HH = OFF_WT + 0x4000000;         // 80MB bf16
static const size_t WS_NEED = OFF_HH + 0x5000000;        // ~236 MB

extern "C" void kernel_launch(void* const* d_in, const int* in_sizes, int n_in,
                              void* d_out, int out_size, void* d_ws, size_t ws_size,
                              hipStream_t stream) {
  (void)in_sizes; (void)n_in; (void)out_size;
  if (ws_size < WS_NEED) return;  // fail visibly rather than corrupt

  const float* x = (const float*)d_in[0];
  const float* cosb = (const float*)d_in[1];
  const float* sinb = (const float*)d_in[2];
  const float* ln1g = (const float*)d_in[3];
  const float* ln1b = (const float*)d_in[4];
  const float* ln2g = (const float*)d_in[5];
  const float* ln2b = (const float*)d_in[6];
  const float* wqkv = (const float*)d_in[7];
  const float* bqkv = (const float*)d_in[8];
  const float* wo = (const float*)d_in[9];
  const float* bo = (const float*)d_in[10];
  const float* gatew = (const float*)d_in[11];
  const float* w1 = (const float*)d_in[12];
  const float* b1 = (const float*)d_in[13];
  const float* w2 = (const float*)d_in[14];
  const float* b2 = (const float*)d_in[15];
  float* out = (float*)d_out;

  char* ws = (char*)d_ws;
  int* topi = (int*)(ws + OFF_TOPI);
  float* tw = (float*)(ws + OFF_TW);
  int* pos = (int*)(ws + OFF_POS);
  f16* h1h = (f16*)(ws + OFF_H);                     // 8MB
  f16* h1l = (f16*)(ws + OFF_H + 0x800000);          // 8MB
  f16* oh = h1h;                                     // reuse (h1 dead post-QKV)
  f16* ol = h1l;
  f16* qkvh = (f16*)(ws + OFF_QKV);                  // 24MB
  f16* qkvl = (f16*)(ws + OFF_QKV + 0x1800000);      // 24MB
  u16* outm = (u16*)(ws + OFF_QKV);                  // reuse (qkv dead post-attn)
  float* h2f = (float*)(ws + OFF_H2F);
  u16* h2b = (u16*)(ws + OFF_H2B);
  u16* buf = (u16*)(ws + OFF_BUF);
  u16* wt = (u16*)(ws + OFF_WT);
  f16* wqkvTh = (f16*)(ws + OFF_WT);                 // 6 MB
  f16* wqkvTl = (f16*)(ws + OFF_WT + 0x600000);      // 6 MB
  f16* woTh = (f16*)(ws + OFF_WT + 0xC00000);        // 2 MB
  f16* woTl = (f16*)(ws + OFF_WT + 0xE00000);        // 2 MB
  float* me_part = (float*)(ws + OFF_WT + 0x1000000);
  u16* hh = (u16*)(ws + OFF_HH);

  // pre-gate path: split-fp16 3-pass MFMA (rel err ~2e-7 -> routing exact)
  ln_kernel<<<4096, 256, 0, stream>>>(x, ln1g, ln1b, nullptr, (u16*)nullptr, h1h, h1l);
  transpose_f32_f16hl<<<dim3(96, 32), 256, 0, stream>>>(wqkv, wqkvTh, wqkvTl, 1024, 3072);
  gemm_f16x3_bt<0><<<dim3(24, 32), 256, 0, stream>>>(h1h, h1l, wqkvTh, wqkvTl, bqkv,
                                                     nullptr, nullptr, qkvh, qkvl,
                                                     4096, 3072, 1024);
  rope_kernel<<<4096, 256, 0, stream>>>(qkvh, qkvl, cosb, sinb);
  transpose_f32_f16hl<<<dim3(32, 32), 256, 0, stream>>>(wo, woTh, woTl, 1024, 1024);
  attn_mfma<<<dim3(32, 32), 256, 0, stream>>>(qkvh, qkvl, oh, ol);
  gemm_f16x3_bt<1><<<dim3(8, 32), 256, 0, stream>>>(oh, ol, woTh, woTl, bo, x,
                                                    out, nullptr, nullptr,
                                                    4096, 1024, 1024);
  ln_kernel<<<4096, 256, 0, stream>>>(out, ln2g, ln2b, h2f, h2b, nullptr, nullptr);
  gate_kernel<<<1024, 256, 0, stream>>>(h2f, gatew, topi, tw, me_part);
  route_kernel<<<1, 256, 0, stream>>>(topi, me_part, pos, out + 4194304);

  // MoE experts: bf16 MFMA (smooth path). No buf memset needed: capacity
  // rows beyond each expert's count are row-independent through both GEMMs
  // and never touched by gather (pos < CAPACITY guard covers exactly the
  // rows scatter wrote).
  moe_scatter<<<8192, 128, 0, stream>>>(h2b, topi, pos, buf);
  transpose_f32_bf16<<<dim3(128, 32, 8), 256, 0, stream>>>(w1, wt, 1024, 4096, 1024L * 4096);
  bgemm_bt<1><<<dim3(32, 10, 8), 256, 0, stream>>>(buf, wt, b1, hh, 1280, 4096, 1024,
                                                   1280L * 1024, 4096L * 1024, 4096, 1280L * 4096);
  transpose_f32_bf16<<<dim3(32, 128, 8), 256, 0, stream>>>(w2, wt, 4096, 1024, 4096L * 1024);
  bgemm_bt<0><<<dim3(8, 10, 8), 256, 0, stream>>>(hh, wt, b2, outm, 1280, 1024, 4096,
                                                  1280L * 4096, 1024L * 4096, 1024, 1280L * 1024);
  moe_gather<<<4096, 256, 0, stream>>>(outm, topi, pos, tw, out);
}